// Round 7
// baseline (138.108 us; speedup 1.0000x reference)
//
#include <hip/hip_runtime.h>
#include <math.h>
#include <stdint.h>

#define VOCAB 100000
#define DIM   128
#define BATCH 16384
#define CMAX  10
#define KNEG  5
#define NSCORE (CMAX + KNEG)
#define JPAD  16            // padded scores per sample (j=15 is a dummy slot)

typedef float f32x4 __attribute__((ext_vector_type(4)));

// Numerically stable log(sigmoid(x)) = min(x,0) - log1p(exp(-|x|))
__device__ __forceinline__ float log_sigmoid(float x) {
    return fminf(x, 0.0f) - log1pf(expf(-fabsf(x)));
}

// DPP-based 32-lane sum: after 5 dependent VALU adds, lane 31 holds
// sum(lanes 0..31) and lane 63 holds sum(lanes 32..63).
#define DPP_ADD_STEP(v, ctrl)                                                  \
    v += __int_as_float(__builtin_amdgcn_update_dpp(                           \
        0, __float_as_int(v), (ctrl), 0xF, 0xF, false))

__device__ __forceinline__ float dpp_reduce32_to_lane31(float v) {
    DPP_ADD_STEP(v, 0x111);  // row_shr:1
    DPP_ADD_STEP(v, 0x112);  // row_shr:2
    DPP_ADD_STEP(v, 0x114);  // row_shr:4
    DPP_ADD_STEP(v, 0x118);  // row_shr:8
    DPP_ADD_STEP(v, 0x142);  // row_bcast:15
    return v;
}

// ---------------------------------------------------------------------------
// Kernel A (R7): one 256-thread block <-> 2 samples. The 2 target rows are
// staged into LDS once (cooperative coalesced load), removing the 4x-redundant
// tv gathers of R6. Each half-wave (32 lanes) computes 4 scores of one sample
// via asm-batched row gathers (all in flight before one s_waitcnt).
// Gathered-bytes law from R4-R6: gather path saturates at ~6.4 TB/s, so time
// tracks bytes: 20 rows/sample -> 17 rows/sample.
// Grid: 8192 blocks, 32768 waves (supply unchanged vs R6).
// ---------------------------------------------------------------------------
__global__ __launch_bounds__(256) void score_kernel(
    const int*   __restrict__ tgt,
    const int*   __restrict__ ctx,
    const int*   __restrict__ neg,
    const float* __restrict__ in_emb,
    const float* __restrict__ out_emb,
    float*       __restrict__ scores,   // [BATCH * JPAD]
    float*       __restrict__ out)
{
    const int tid = threadIdx.x;
    const int h   = tid >> 5;          // half-wave 0..7
    const int sub = tid & 31;          // lane in half-wave
    const int s   = h >> 2;            // sample-in-block 0..1
    const int g   = h & 3;             // j-group 0..3
    const int b   = blockIdx.x * 2 + s;
    const int j0  = g * 4;

    if (blockIdx.x == 0 && tid < 2) out[tid] = 0.0f;

    __shared__ float ldsT[2 * DIM];    // the block's two target rows

    // ---- cooperative tv stage: 256 threads load 2 rows (2x512B coalesced) --
    {
        const int ss = tid >> 7;       // which sample's row
        const int e  = tid & 127;      // element
        const int tw = tgt[blockIdx.x * 2 + ss];
        ldsT[ss * DIM + e] = in_emb[(size_t)tw * DIM + e];
    }

    // ---- index loads (independent, before the barrier) ----
    int words[4];
#pragma unroll
    for (int jj = 0; jj < 4; ++jj) {
        const int j = j0 + jj;
        if (j < CMAX)        words[jj] = ctx[b * CMAX + j];
        else if (j < NSCORE) words[jj] = neg[b * KNEG + (j - CMAX)];
        else                 words[jj] = 0;   // dummy slot j=15 -> hot row 0
    }

    __syncthreads();

    // ---- issue all 4 row gathers (asm, all in flight) ----
    const uint32_t sub16 = (uint32_t)sub * 16u;
    f32x4 rv[4];
#pragma unroll
    for (int jj = 0; jj < 4; ++jj) {
        uint32_t off = (uint32_t)words[jj] * (DIM * 4u) + sub16;
        asm volatile("global_load_dwordx4 %0, %1, %2"
                     : "=v"(rv[jj]) : "v"(off), "s"(out_emb));
    }

    // tv fragment from LDS while gathers are in flight (compiler inserts
    // the lgkmcnt wait; gather drain is the asm vmcnt below).
    const float4 tv = ((const float4*)ldsT)[s * 32 + sub];

    asm volatile("s_waitcnt vmcnt(0)"
                 : "+v"(rv[0]), "+v"(rv[1]), "+v"(rv[2]), "+v"(rv[3])
                 :
                 : "memory");

    // ---- 4 dots + 4 independent DPP reductions ----
    float p[4];
#pragma unroll
    for (int jj = 0; jj < 4; ++jj) {
        float d = tv.x * rv[jj].x + tv.y * rv[jj].y +
                  tv.z * rv[jj].z + tv.w * rv[jj].w;
        p[jj] = dpp_reduce32_to_lane31(d);
    }

    if (sub == 31) {
        float* sc = scores + (size_t)b * JPAD + j0;
#pragma unroll
        for (int jj = 0; jj < 4; ++jj)
            if (j0 + jj < NSCORE) sc[jj] = p[jj];
    }
}

// ---------------------------------------------------------------------------
// Kernel B: one thread per sample. Reads 1 MB of scores from L2.
// ---------------------------------------------------------------------------
__global__ __launch_bounds__(256) void loss_kernel(
    const float* __restrict__ scores,   // [BATCH * JPAD]
    const int*   __restrict__ lens,
    float*       __restrict__ out)
{
    const int tid = threadIdx.x;
    const int b   = blockIdx.x * 256 + tid;   // 64 blocks cover BATCH exactly

    const int len = lens[b];
    const float* s = scores + (size_t)b * JPAD;

    float sc[NSCORE];
#pragma unroll
    for (int j = 0; j < NSCORE; ++j) sc[j] = s[j];

    float pos_acc = 0.0f;
#pragma unroll
    for (int c = 0; c < CMAX; ++c)
        if (c < len) pos_acc += log_sigmoid(sc[c]);
    float neg_acc = 0.0f;
#pragma unroll
    for (int k = 0; k < KNEG; ++k)
        neg_acc += log_sigmoid(-sc[CMAX + k]);

    float pos_per = 0.0f, neg_per = 0.0f;
    if (len > 0) {
        pos_per = -pos_acc / (float)len;
        neg_per = -neg_acc * (1.0f / KNEG);
    }

    // wave reduction (64 lanes), then LDS across the 4 waves, then atomics
#pragma unroll
    for (int m = 32; m >= 1; m >>= 1) {
        pos_per += __shfl_xor(pos_per, m, 64);
        neg_per += __shfl_xor(neg_per, m, 64);
    }
    __shared__ float s_pos[4];
    __shared__ float s_neg[4];
    const int wave = tid >> 6;
    if ((tid & 63) == 0) { s_pos[wave] = pos_per; s_neg[wave] = neg_per; }
    __syncthreads();
    if (tid == 0) {
        float ps = s_pos[0] + s_pos[1] + s_pos[2] + s_pos[3];
        float ns = s_neg[0] + s_neg[1] + s_neg[2] + s_neg[3];
        atomicAdd(&out[0], ps * (1.0f / BATCH));
        atomicAdd(&out[1], ns * (1.0f / BATCH));
    }
}

extern "C" void kernel_launch(void* const* d_in, const int* in_sizes, int n_in,
                              void* d_out, int out_size, void* d_ws, size_t ws_size,
                              hipStream_t stream) {
    const int*   tgt     = (const int*)  d_in[0];
    const int*   ctx     = (const int*)  d_in[1];
    const int*   lens    = (const int*)  d_in[2];
    const int*   neg     = (const int*)  d_in[3];
    const float* in_emb  = (const float*)d_in[4];
    const float* out_emb = (const float*)d_in[5];
    float* out    = (float*)d_out;
    float* scores = (float*)d_ws;       // BATCH*JPAD*4 = 1 MiB scratch

    // 8192 blocks; each handles 2 samples (8 half-wave tasks of 4 scores).
    score_kernel<<<BATCH / 2, 256, 0, stream>>>(
        tgt, ctx, neg, in_emb, out_emb, scores, out);

    loss_kernel<<<BATCH / 256, 256, 0, stream>>>(scores, lens, out);
}

// Round 8
// 136.086 us; speedup vs baseline: 1.0149x; 1.0149x over previous
//
#include <hip/hip_runtime.h>
#include <math.h>
#include <stdint.h>

#define VOCAB 100000
#define DIM   128
#define BATCH 16384
#define CMAX  10
#define KNEG  5
#define NSCORE (CMAX + KNEG)
#define JPAD  16            // scores stride per sample (slot 15 unused)

typedef float f32x4 __attribute__((ext_vector_type(4)));

// Numerically stable log(sigmoid(x)) = min(x,0) - log1p(exp(-|x|))
__device__ __forceinline__ float log_sigmoid(float x) {
    return fminf(x, 0.0f) - log1pf(expf(-fabsf(x)));
}

// DPP-based 32-lane sum: after 5 dependent VALU adds, lane 31 holds
// sum(lanes 0..31) and lane 63 holds sum(lanes 32..63).
#define DPP_ADD_STEP(v, ctrl)                                                  \
    v += __int_as_float(__builtin_amdgcn_update_dpp(                           \
        0, __float_as_int(v), (ctrl), 0xF, 0xF, false))

__device__ __forceinline__ float dpp_reduce32_to_lane31(float v) {
    DPP_ADD_STEP(v, 0x111);  // row_shr:1
    DPP_ADD_STEP(v, 0x112);  // row_shr:2
    DPP_ADD_STEP(v, 0x114);  // row_shr:4
    DPP_ADD_STEP(v, 0x118);  // row_shr:8
    DPP_ADD_STEP(v, 0x142);  // row_bcast:15
    return v;
}

// ---------------------------------------------------------------------------
// Kernel A (R8): one half-wave (32 lanes) per (sample b, j-group g) task,
// g in 0..2, each task computes 5 scores j = g*5 .. g*5+4 (15 exactly, no
// dummy slot). Barrier-free (R7 showed any pre-gather __syncthreads drops
// throughput off the ~6.4 TB/s gathered-bytes law). All 6 row gathers
// (tv + rv[0..4]) issued via asm before one s_waitcnt vmcnt(0).
// Gathered rows/sample: 18 (R6: 20) -> 151 MB total.
// 49,152 tasks, 8 per block -> 6144 blocks of 256 threads.
// ---------------------------------------------------------------------------
__global__ __launch_bounds__(256) void score_kernel(
    const int*   __restrict__ tgt,
    const int*   __restrict__ ctx,
    const int*   __restrict__ neg,
    const float* __restrict__ in_emb,
    const float* __restrict__ out_emb,
    float*       __restrict__ scores,   // [BATCH * JPAD]
    float*       __restrict__ out)
{
    const int tid  = threadIdx.x;
    const int sub  = tid & 31;                              // lane in half-wave
    const int task = (blockIdx.x * 256 + tid) >> 5;         // global (b,g) id
    const int b    = task / 3;                              // sample
    const int g    = task - b * 3;                          // j-group 0..2
    const int j0   = g * 5;

    if (blockIdx.x == 0 && tid < 2) out[tid] = 0.0f;

    // ---- index loads (independent; uniform within half-wave) ----
    const int t_word = tgt[b];
    int words[5];
#pragma unroll
    for (int jj = 0; jj < 5; ++jj) {
        const int j = j0 + jj;
        words[jj] = (j < CMAX) ? ctx[b * CMAX + j]
                               : neg[b * KNEG + (j - CMAX)];
    }

    // ---- issue all 6 row gathers, then one waitcnt ----
    const uint32_t sub16 = (uint32_t)sub * 16u;

    f32x4 tv;
    {
        uint32_t off = (uint32_t)t_word * (DIM * 4u) + sub16;
        asm volatile("global_load_dwordx4 %0, %1, %2"
                     : "=v"(tv) : "v"(off), "s"(in_emb));
    }
    f32x4 rv[5];
#pragma unroll
    for (int jj = 0; jj < 5; ++jj) {
        uint32_t off = (uint32_t)words[jj] * (DIM * 4u) + sub16;
        asm volatile("global_load_dwordx4 %0, %1, %2"
                     : "=v"(rv[jj]) : "v"(off), "s"(out_emb));
    }
    asm volatile("s_waitcnt vmcnt(0)"
                 : "+v"(tv), "+v"(rv[0]), "+v"(rv[1]), "+v"(rv[2]),
                   "+v"(rv[3]), "+v"(rv[4])
                 :
                 : "memory");

    // ---- 5 dots + 5 independent DPP reductions ----
    float p[5];
#pragma unroll
    for (int jj = 0; jj < 5; ++jj) {
        float d = tv.x * rv[jj].x + tv.y * rv[jj].y +
                  tv.z * rv[jj].z + tv.w * rv[jj].w;
        p[jj] = dpp_reduce32_to_lane31(d);
    }

    if (sub == 31) {
        float* s = scores + (size_t)b * JPAD + j0;
#pragma unroll
        for (int jj = 0; jj < 5; ++jj) s[jj] = p[jj];
    }
}

// ---------------------------------------------------------------------------
// Kernel B: one thread per sample. Reads 1 MB of scores from L2.
// ---------------------------------------------------------------------------
__global__ __launch_bounds__(256) void loss_kernel(
    const float* __restrict__ scores,   // [BATCH * JPAD]
    const int*   __restrict__ lens,
    float*       __restrict__ out)
{
    const int tid = threadIdx.x;
    const int b   = blockIdx.x * 256 + tid;   // 64 blocks cover BATCH exactly

    const int len = lens[b];
    const float* s = scores + (size_t)b * JPAD;

    float sc[NSCORE];
#pragma unroll
    for (int j = 0; j < NSCORE; ++j) sc[j] = s[j];

    float pos_acc = 0.0f;
#pragma unroll
    for (int c = 0; c < CMAX; ++c)
        if (c < len) pos_acc += log_sigmoid(sc[c]);
    float neg_acc = 0.0f;
#pragma unroll
    for (int k = 0; k < KNEG; ++k)
        neg_acc += log_sigmoid(-sc[CMAX + k]);

    float pos_per = 0.0f, neg_per = 0.0f;
    if (len > 0) {
        pos_per = -pos_acc / (float)len;
        neg_per = -neg_acc * (1.0f / KNEG);
    }

    // wave reduction (64 lanes), then LDS across the 4 waves, then atomics
#pragma unroll
    for (int m = 32; m >= 1; m >>= 1) {
        pos_per += __shfl_xor(pos_per, m, 64);
        neg_per += __shfl_xor(neg_per, m, 64);
    }
    __shared__ float s_pos[4];
    __shared__ float s_neg[4];
    const int wave = tid >> 6;
    if ((tid & 63) == 0) { s_pos[wave] = pos_per; s_neg[wave] = neg_per; }
    __syncthreads();
    if (tid == 0) {
        float ps = s_pos[0] + s_pos[1] + s_pos[2] + s_pos[3];
        float ns = s_neg[0] + s_neg[1] + s_neg[2] + s_neg[3];
        atomicAdd(&out[0], ps * (1.0f / BATCH));
        atomicAdd(&out[1], ns * (1.0f / BATCH));
    }
}

extern "C" void kernel_launch(void* const* d_in, const int* in_sizes, int n_in,
                              void* d_out, int out_size, void* d_ws, size_t ws_size,
                              hipStream_t stream) {
    const int*   tgt     = (const int*)  d_in[0];
    const int*   ctx     = (const int*)  d_in[1];
    const int*   lens    = (const int*)  d_in[2];
    const int*   neg     = (const int*)  d_in[3];
    const float* in_emb  = (const float*)d_in[4];
    const float* out_emb = (const float*)d_in[5];
    float* out    = (float*)d_out;
    float* scores = (float*)d_ws;       // BATCH*JPAD*4 = 1 MiB scratch

    // 49,152 (b,g) tasks, 8 tasks (of 32 lanes) per 256-thread block.
    score_kernel<<<(BATCH * 3) / 8, 256, 0, stream>>>(
        tgt, ctx, neg, in_emb, out_emb, scores, out);

    loss_kernel<<<BATCH / 256, 256, 0, stream>>>(scores, lens, out);
}